// Round 1
// baseline (273.797 us; speedup 1.0000x reference)
//
#include <hip/hip_runtime.h>

#define N_RAYS 65536
#define N_SAMPLES 128
#define RPB 8   // rays per block (256 thr = 4 waves, 2 rays/wave, 32 lanes/ray)

// async global->LDS, 16B per lane. LDS dest is wave-uniform base + lane*16;
// global src is per-lane (guide §5, m97/m104).
__device__ __forceinline__ void gll16(const float* g, float* l) {
    __builtin_amdgcn_global_load_lds(
        (const __attribute__((address_space(1))) void*)g,
        (__attribute__((address_space(3))) void*)l,
        16, 0, 0);
}

__device__ __forceinline__ float sigmoidf(float x) {
    return __fdividef(1.0f, 1.0f + __expf(-x));
}

__global__ __launch_bounds__(256, 8) void neus_kernel(
    const float* __restrict__ sdf,
    const float* __restrict__ color,
    const float* __restrict__ z_vals,
    const float* __restrict__ grad_theta,
    const float* __restrict__ rays_d,
    const float* __restrict__ s_ptr,
    const float* __restrict__ car_ptr,
    float* __restrict__ out_pixel,     // [N,3]
    float* __restrict__ out_invdepth,  // [N]
    float* __restrict__ out_weight)    // [N,S]
{
    // One buffer, reused grad -> color. 12 KiB -> 8 blocks/CU -> 32 waves/CU.
    __shared__ __align__(16) float lds[RPB * N_SAMPLES * 3];

    const int tid = threadIdx.x;
    const int l   = tid & 31;          // lane within ray (owns samples 4l..4l+3)
    const int r   = tid >> 5;          // ray within block (0..7)
    const int wv  = tid >> 6;          // wave (0..3); wave w owns rays 2w,2w+1
    const int l64 = tid & 63;
    const int ray = blockIdx.x * RPB + r;

    const size_t base  = (size_t)ray * N_SAMPLES;
    const size_t base3 = (size_t)blockIdx.x * (RPB * N_SAMPLES * 3);

    // ---- stage grad_theta: 12 chunks x 1024B, 3 per wave, WAVE-PRIVATE ----
    // wave w stages floats [w*768, w*768+768) == exactly its own rays 2w,2w+1
    // -> no __syncthreads needed anywhere; plain waitcnt suffices.
    {
        const float* g = grad_theta + base3;
        #pragma unroll
        for (int k = 0; k < 3; ++k) {
            const int q = wv * 3 + k;
            gll16(g + q * 256 + l64 * 4, &lds[q * 256]);
        }
    }

    // contiguous 16B/lane register loads (lanes 0..63 cover 2 adjacent rays)
    const float4 sd = *(const float4*)(sdf    + base + 4 * l);
    const float4 zz = *(const float4*)(z_vals + base + 4 * l);
    const float rdx = rays_d[ray * 3 + 0];
    const float rdy = rays_d[ray * 3 + 1];
    const float rdz = rays_d[ray * 3 + 2];
    const float sv  = s_ptr[0];
    const float car = car_ptr[0];
    const float omc = 1.0f - car;

    asm volatile("s_waitcnt vmcnt(0)" ::: "memory");   // grad (and sd/zz) resident

    // this lane's 12 grad floats: samples 4l..4l+3, AoS
    const int fo = r * 384 + 12 * l;
    const float4 gA = *(const float4*)&lds[fo + 0];
    const float4 gB = *(const float4*)&lds[fo + 4];
    const float4 gC = *(const float4*)&lds[fo + 8];

    asm volatile("s_waitcnt lgkmcnt(0)" ::: "memory"); // grad reads done -> buffer reusable

    // ---- stage color into the same wave-private region; latency hides under
    //      the alpha/scan compute below ----
    {
        const float* c = color + base3;
        #pragma unroll
        for (int k = 0; k < 3; ++k) {
            const int q = wv * 3 + k;
            gll16(c + q * 256 + l64 * 4, &lds[q * 256]);
        }
    }

    // true cosine per sample
    const float tc0 = rdx * gA.x + rdy * gA.y + rdz * gA.z;
    const float tc1 = rdx * gA.w + rdy * gB.x + rdz * gB.y;
    const float tc2 = rdx * gB.z + rdy * gB.w + rdz * gC.x;
    const float tc3 = rdx * gC.y + rdy * gC.z + rdz * gC.w;

    auto iter_cos = [&](float tc) -> float {
        float a = fmaxf(fmaf(tc, -0.5f, 0.5f), 0.0f);
        float b = fmaxf(-tc, 0.0f);
        return -(a * omc + b * car);
    };
    const float ic0 = iter_cos(tc0);
    const float ic1 = iter_cos(tc1);
    const float ic2 = iter_cos(tc2);
    const float ic3 = iter_cos(tc3);

    // dists: 3 in-register, 1 from neighbor lane (width-32 confined)
    const float zn = __shfl_down(zz.x, 1, 32);   // z[4l+4]; garbage at l==31 (unused)
    const float d0 = zz.y - zz.x;
    const float d1 = zz.z - zz.y;
    const float d2 = zz.w - zz.z;
    const float d3 = zn   - zz.w;

    auto alpha_f = [&](float sdv, float ic, float d) -> float {
        float h  = ic * d * 0.5f;
        float pc = sigmoidf((sdv - h) * sv);
        float nc = sigmoidf((sdv + h) * sv);
        float a  = __fdividef(pc - nc + 1e-5f, pc + 1e-5f);
        return fminf(fmaxf(a, 0.0f), 1.0f);
    };
    const float a0 = alpha_f(sd.x, ic0, d0);
    const float a1 = alpha_f(sd.y, ic1, d1);
    const float a2 = alpha_f(sd.z, ic2, d2);
    const float a3 = (l == 31) ? 0.0f : alpha_f(sd.w, ic3, d3); // sample 127: appended zero

    const float om0 = 1.0f - a0;
    const float om1 = 1.0f - a1;
    const float om2 = 1.0f - a2;
    const float om3 = 1.0f - a3;

    // width-32 exclusive product scan of per-lane 4-sample product (5 steps)
    float scan = om0 * om1 * om2 * om3;
    #pragma unroll
    for (int off = 1; off < 32; off <<= 1) {
        float v = __shfl_up(scan, off, 32);
        if (l >= off) scan *= v;
    }
    float excl = __shfl_up(scan, 1, 32);
    if (l == 0) excl = 1.0f;

    // weights; ref prepends ZERO transmittance at sample 0 -> w[0]=0
    float t  = excl;
    const float w0 = (l == 0) ? 0.0f : t * a0;
    t *= om0; const float w1 = t * a1;
    t *= om1; const float w2 = t * a2;
    t *= om2; const float w3 = t * a3;   // l==31: a3==0 -> 0

    // invdepth partial (doesn't need color; overlaps color staging wait)
    float inv = w0 * __fdividef(1.0f, zz.x) + w1 * __fdividef(1.0f, zz.y)
              + w2 * __fdividef(1.0f, zz.z) + w3 * __fdividef(1.0f, zz.w);

    asm volatile("s_waitcnt vmcnt(0)" ::: "memory");   // color resident in LDS

    const float4 cA = *(const float4*)&lds[fo + 0];
    const float4 cB = *(const float4*)&lds[fo + 4];
    const float4 cC = *(const float4*)&lds[fo + 8];

    // contiguous 16B/lane weight store
    *(float4*)(out_weight + base + 4 * l) = make_float4(w0, w1, w2, w3);

    // pixel partials (AoS unpack: c[4l]=(A.x,A.y,A.z), c[4l+1]=(A.w,B.x,B.y),
    //                 c[4l+2]=(B.z,B.w,C.x), c[4l+3]=(C.y,C.z,C.w))
    float pr = w0 * cA.x + w1 * cA.w + w2 * cB.z + w3 * cC.y;
    float pg = w0 * cA.y + w1 * cB.x + w2 * cB.w + w3 * cC.z;
    float pb = w0 * cA.z + w1 * cB.y + w2 * cC.x + w3 * cC.w;

    // width-32 butterfly reduction (5 steps x 4 values)
    #pragma unroll
    for (int off = 16; off > 0; off >>= 1) {
        pr  += __shfl_xor(pr,  off, 32);
        pg  += __shfl_xor(pg,  off, 32);
        pb  += __shfl_xor(pb,  off, 32);
        inv += __shfl_xor(inv, off, 32);
    }

    if (l == 0) {
        out_pixel[ray * 3 + 0] = pr;
        out_pixel[ray * 3 + 1] = pg;
        out_pixel[ray * 3 + 2] = pb;
        out_invdepth[ray]      = inv;
    }
}

extern "C" void kernel_launch(void* const* d_in, const int* in_sizes, int n_in,
                              void* d_out, int out_size, void* d_ws, size_t ws_size,
                              hipStream_t stream) {
    const float* sdf        = (const float*)d_in[0];
    const float* color      = (const float*)d_in[1];
    const float* z_vals     = (const float*)d_in[2];
    const float* grad_theta = (const float*)d_in[3];
    const float* rays_d     = (const float*)d_in[4];
    const float* s_ptr      = (const float*)d_in[5];
    const float* car_ptr    = (const float*)d_in[6];

    float* out          = (float*)d_out;
    float* out_pixel    = out;                        // N*3
    float* out_invdepth = out + (size_t)N_RAYS * 3;   // N
    float* out_weight   = out + (size_t)N_RAYS * 4;   // N*S

    dim3 block(256);                  // 4 waves = 8 rays per block
    dim3 grid(N_RAYS / RPB);          // 8192 blocks

    neus_kernel<<<grid, block, 0, stream>>>(
        sdf, color, z_vals, grad_theta, rays_d, s_ptr, car_ptr,
        out_pixel, out_invdepth, out_weight);
}